// Round 13
// baseline (172.108 us; speedup 1.0000x reference)
//
#include <hip/hip_runtime.h>
#include <hip/hip_bf16.h>
#include <math.h>

#define BB 8
#define CC 128
#define DD 64
#define TT 64
#define PP 4096
#define H1 66
#define LW 20
#define MARGINF 0.1f
#define NEG_SENTINEL -1.0e30f

// workspace layout (float offsets)
#define Y0_OFF   0            // y0w bf16 channel-last [8][66][66][128] = 2230272 f
#define VT_OFF   2230272      // vT bf16 [8][64][64][128] = 2097152 f
#define BP0_OFF  4327424      // Bpack(Wc0) 16x16 layout = 73728 f
#define NL_OFF   4401152      // per-sentence neg-loss [8] (old BP1 slot, unused gap)
#define W0_OFF   4479236      // weight0 [66][66] = 4356
#define W1_OFF   4483592      // weight1 [64][64] = 4096
#define G0_OFF   4487688      // [8][128]
#define G1_OFF   4488712      // [8][128]
#define S_OFF    4489736      // si [8][4096] = 32768 (diag maps only)
#define SCP_OFF  4522504      // packed scores u64 [64] = 128 f
#define BP1S_OFF 4522632      // 8x gate-scaled Bpack(Wc1*g0[i]) = 8*73728 f = 589824 f
// total ≈ 5112456 floats ≈ 20.5 MB

typedef __attribute__((ext_vector_type(8))) short bf16x8;
typedef __attribute__((ext_vector_type(4))) float f32x4;

// conv1 LDS (row,col) stride in shorts: 44 (=88B), conflict-light b128 access
#define ASTR 44
// conv2 full-depth tile: per-cic plane, (row,col) stride 36 shorts (72B) —
// same bank-spread class as 44 (odd multiplier mod 16), fits 2 blocks/CU
#define A2STR 36
#define A2PL  (4 * 66 * A2STR)    // 9504 shorts per cic plane

__device__ __forceinline__ unsigned f2bf(float f) {
  union { float f; unsigned u; } v; v.f = f;
  unsigned r = v.u + 0x7fffu + ((v.u >> 16) & 1u);   // RNE (setup only)
  return r >> 16;
}
__device__ __forceinline__ float bf2f(unsigned hw) {
  union { unsigned u; float f; } v; v.u = hw << 16;
  return v.f;
}
// native cast: compiler emits v_cvt_pk for pairs (m240)
__device__ __forceinline__ unsigned cvt_bf(float x) {
  __hip_bfloat16 h = __float2bfloat16(x);
  union { __hip_bfloat16 h; unsigned short u; } cv; cv.h = h;
  return (unsigned)cv.u;
}

// sign-select on 2 packed bf16: keep half iff sign(v) == wanted sign bit in W.
// relu(g*v)*Wc1 == select(v) * (Wc1*g), select(v) = g>0 ? max(v,0) : min(v,0)
__device__ __forceinline__ unsigned selbf(unsigned d, unsigned W) {
  unsigned diff = (d ^ W) & 0x80008000u;     // sign mismatch bits
  unsigned full = (diff >> 15) * 0xFFFFu;    // expand to half-word masks
  return d & ~full;                          // zero mismatched halves
}

// ---------------- setup + gates fused (B1S lives in conv1 launch)
__global__ __launch_bounds__(256) void setup_kernel(
    const float* __restrict__ vmap, const float* __restrict__ v_mask,
    const float* __restrict__ Wc0,
    const float* __restrict__ words, const float* __restrict__ w_masks,
    const float* __restrict__ Wp0, const float* __restrict__ bp0,
    const float* __restrict__ Wp1, const float* __restrict__ bp1,
    float* __restrict__ ws)
{
  __shared__ float smem[64 * 129];
  int bid = blockIdx.x;
  int t = threadIdx.x;

  if (bid < 576) {
    // B0 pack (unscaled)
    unsigned short* dst = (unsigned short*)(ws + BP0_OFF);
    int idx = bid * 256 + t;
    int j    = idx & 7;
    int lane = (idx >> 3) & 63;
    int cog  = (idx >> 9) & 7;
    int cic  = (idx >> 12) & 3;
    int kk   = idx >> 14;
    int co = cog * 16 + (lane & 15);
    int ci = cic * 32 + (lane >> 4) * 8 + j;
    dst[idx] = (unsigned short)f2bf(Wc0[(co * CC + ci) * 9 + kk]);
  } else if (bid < 1088) {
    unsigned short* vT = (unsigned short*)(ws + VT_OFF);
    int b = bid - 576;                   // 576 % 8 == 0 -> XCD = b & 7
    int n = b & 7, y = b >> 3;           // XCD-aligned: vT[n] stays in XCD n's L2
    int x = t & 63, c4 = t >> 6;
    for (int rep = 0; rep < 32; ++rep) {
      int ci = rep * 4 + c4;
      smem[x * 129 + ci] = vmap[(((size_t)n * CC + ci) * DD + y) * TT + x];
    }
    __syncthreads();
    for (int rep = 0; rep < 16; ++rep) {
      int v = t + rep * 256;
      int xx = v >> 6, cip = v & 63;
      float a = smem[xx * 129 + cip * 2];
      float b2 = smem[xx * 129 + cip * 2 + 1];
      unsigned pk = f2bf(a) | (f2bf(b2) << 16);
      *(unsigned*)&vT[(((size_t)(n * DD + y) * TT + xx)) * CC + cip * 2] = pk;
    }
  } else if (bid == 1088) {
    if (t < 128) ((unsigned*)(ws + SCP_OFF))[t] = 0u;   // zero packed scores
    float* w0 = ws + W0_OFF;
    float* w1 = ws + W1_OFF;
    for (int idx = t; idx < H1 * H1; idx += 256) {
      int y = idx / H1, x = idx % H1;
      float cnt = 0.f;
      for (int ky = 0; ky < 3; ++ky)
        for (int kx = 0; kx < 3; ++kx) {
          int iy = y + ky - 2, ix = x + kx - 2;
          if (iy >= 0 && iy < DD && ix >= 0 && ix < TT) cnt += v_mask[iy * TT + ix];
        }
      w0[idx] = (cnt > 0.f) ? 1.f / fmaxf(cnt, 1.f) : 0.f;
    }
    __syncthreads();
    for (int idx = t; idx < DD * TT; idx += 256) {
      int y = idx / TT, x = idx % TT;
      float cnt = 0.f;
      for (int ky = 0; ky < 3; ++ky)
        for (int kx = 0; kx < 3; ++kx)
          cnt += (w0[(y + ky) * H1 + (x + kx)] > 0.f) ? 1.f : 0.f;
      w1[idx] = (cnt > 0.f) ? 1.f / fmaxf(cnt, 1.f) : 0.f;
    }
  } else {
    // gates: pooled words -> g0,g1 (consumed by NEXT launch's B1S blocks)
    int i = bid - 1089;
    if (t < CC) {
      float wsum = 0.f, acc = 0.f;
      for (int l = 0; l < LW; ++l) {
        float wm = w_masks[i * LW + l];
        wsum += wm;
        acc += words[(i * LW + l) * CC + t] * wm;
      }
      smem[t] = acc / fmaxf(wsum, 1.f);
    }
    __syncthreads();
    {
      int c = t & 127;
      const float* Wp = (t < 128) ? Wp0 : Wp1;
      const float* bp = (t < 128) ? bp0 : bp1;
      float a = bp[c];
      for (int k = 0; k < CC; ++k) a += smem[k] * Wp[k * CC + c];
      float g = tanhf(a);
      float* gout = ws + ((t < 128) ? G0_OFF : G1_OFF);
      gout[i * CC + c] = g;
    }
  }
}

// conv1 (co-split, 1 row x 64 co per block) + B1S pack riding along (R28 WIN)
__global__ __launch_bounds__(256, 3) void conv1_mfma(
    const float* __restrict__ bc0, const float* __restrict__ Wc1,
    float* __restrict__ ws)
{
  __shared__ unsigned short Alds[3 * 68 * ASTR];   // 17952 B

  int t = threadIdx.x;
  int id = blockIdx.x;

  if (id >= 1056) {
    // B1S pack: read each Wc1 element ONCE, write 8 gate-scaled copies
    float* smem = (float*)Alds;                    // 4KB alias
    for (int v = t; v < 8 * CC; v += 256) smem[v] = ws[G0_OFF + v];
    __syncthreads();
    int idx = (id - 1056) * 256 + t;
    int j    = idx & 7;
    int lane = (idx >> 3) & 63;
    int cog  = (idx >> 9) & 7;
    int cic  = (idx >> 12) & 3;
    int kk   = idx >> 14;
    int co = cog * 16 + (lane & 15);
    int ci = cic * 32 + (lane >> 4) * 8 + j;
    float wv = Wc1[(co * CC + ci) * 9 + kk];
    unsigned short* dst = (unsigned short*)(ws + BP1S_OFF);
#pragma unroll
    for (int si = 0; si < 8; ++si)
      dst[si * 147456 + idx] = (unsigned short)f2bf(wv * smem[si * CC + ci]);
    return;
  }

  const unsigned short* vT = (const unsigned short*)(ws + VT_OFF);
  const unsigned short* Bp = (const unsigned short*)(ws + BP0_OFF);
  const float* w0arr = ws + W0_OFF;
  unsigned short* y0w = (unsigned short*)(ws + Y0_OFF);

  int n  = id & 7;                         // XCD-aligned
  int ch = (id >> 3) & 1;                  // co half 0..1
  int r0 = id >> 4;                        // output row 0..65
  int lane = t & 63, w = t >> 6;           // w = 16-co group within half
  int l15 = lane & 15, l4 = lane >> 4;
  int s = ch * 4 + w;                      // 16-co group 0..7
  int co0 = s * 16;

  f32x4 acc[5];
#pragma unroll
  for (int mf = 0; mf < 5; ++mf) acc[mf] = (f32x4){0.f, 0.f, 0.f, 0.f};

  for (int cic = 0; cic < 4; ++cic) {
    __syncthreads();
    for (int u = t; u < 816; u += 256) {
      int cig = u & 3, rest = u >> 2;
      int col = rest % 68, r = rest / 68;
      int iy = r0 - 2 + r, ix = col - 2;
      uint4 val = {0u, 0u, 0u, 0u};
      if (iy >= 0 && iy < DD && ix >= 0 && ix < TT)
        val = *(const uint4*)&vT[(((size_t)(n * DD + iy) * TT + ix)) * CC + cic * 32 + cig * 8];
      *(uint4*)&Alds[(r * 68 + col) * ASTR + cig * 8] = val;
    }
    __syncthreads();
    __builtin_amdgcn_s_setprio(1);
#pragma unroll
    for (int kk = 0; kk < 9; ++kk) {
      int ky = kk / 3, kx = kk % 3;
      bf16x8 af[5], bfr;
#pragma unroll
      for (int mf = 0; mf < 5; ++mf) {
        int c = mf * 16 + l15;
        int cc = c > 65 ? 65 : c;
        af[mf] = *(const bf16x8*)&Alds[(ky * 68 + cc + kx) * ASTR + l4 * 8];
      }
      bfr = *(const bf16x8*)&Bp[(((kk * 4 + cic) * 8 + s) * 64 + lane) * 8];
#pragma unroll
      for (int mf = 0; mf < 5; ++mf)
        acc[mf] = __builtin_amdgcn_mfma_f32_16x16x32_bf16(af[mf], bfr, acc[mf], 0, 0, 0);
    }
    __builtin_amdgcn_s_setprio(0);
  }

  int y = r0;
  {
    int co = co0 + l15;
    float bcv = bc0[co];
#pragma unroll
    for (int mf = 0; mf < 5; ++mf)
#pragma unroll
      for (int rg = 0; rg < 4; ++rg) {
        int c = mf * 16 + l4 * 4 + rg;
        if (c < H1) {
          float v = (acc[mf][rg] + bcv) * w0arr[y * H1 + c];
          y0w[((size_t)(n * H1 + y) * H1 + c) * CC + co] = (unsigned short)cvt_bf(v);
        }
      }
  }
}

// conv2 R29: 4-sentence blocks — stage the y0w tile RAW, ONCE, all 4 cic
// planes (76KB LDS), then serially compute i = ip*4..ip*4+3 applying selbf
// at A-fragment read (mask = 1 uint4 from LDS). Staging volume /4, MFMA per
// staged byte x4. Grid (32, 8n x 2ip) = 512 = 2 blocks/CU (overlap kept,
// R23 lesson); acc stays [4][4] = 64 AGPR one-i-at-a-time (register law);
// "#pragma unroll 1" on the i-loop prevents 4x live-state blowup.
__global__ __launch_bounds__(256, 2) void conv2_mfma(
    const float* __restrict__ bc1, const float* __restrict__ W2d,
    const float* __restrict__ b2d, const float* __restrict__ v_mask,
    const int* __restrict__ valid_num, float* __restrict__ ws,
    float* __restrict__ out)
{
  const unsigned short* y0w = (const unsigned short*)(ws + Y0_OFF);
  const float* w1m = ws + W1_OFF;
  const float* g0 = ws + G0_OFF;
  const float* g1 = ws + G1_OFF;
  unsigned long long* scp = (unsigned long long*)(ws + SCP_OFF);

  __shared__ unsigned short Alds[4 * A2PL];        // 76032 B (4 cic planes)
  __shared__ unsigned msk[4][16][4];               // masks for this block's 4 i
  __shared__ float redl[2][2][64];
  __shared__ unsigned long long kred[2];

  int t = threadIdx.x;
  int r0 = blockIdx.x;                        // output rows r0*2, r0*2+1
  int ip = blockIdx.y & 1, n = blockIdx.y >> 1;  // i-group, video
  int lane = t & 63, w = t >> 6;
  int wr = w >> 1, wc = w & 1;                // wr = row, wc = co half
  int l15 = lane & 15, l4 = lane >> 4;

  if (t < 64) {                               // t = ii*16+g -> masks for i=ip*4+ii
    int ii = t >> 4, g = t & 15;
    int i = ip * 4 + ii;
    int ch = g * 8;
    msk[ii][g][0] = (g0[i * CC + ch + 0] > 0.f ? 0u : 0x8000u) | (g0[i * CC + ch + 1] > 0.f ? 0u : 0x80000000u);
    msk[ii][g][1] = (g0[i * CC + ch + 2] > 0.f ? 0u : 0x8000u) | (g0[i * CC + ch + 3] > 0.f ? 0u : 0x80000000u);
    msk[ii][g][2] = (g0[i * CC + ch + 4] > 0.f ? 0u : 0x8000u) | (g0[i * CC + ch + 5] > 0.f ? 0u : 0x80000000u);
    msk[ii][g][3] = (g0[i * CC + ch + 6] > 0.f ? 0u : 0x8000u) | (g0[i * CC + ch + 7] > 0.f ? 0u : 0x80000000u);
  }

  // stage RAW tile once: 4 rows x 66 cols x 4 cic x 4 cig = 4224 uint4s
  for (int u = t; u < 4224; u += 256) {
    int cig = u & 3, cic = (u >> 2) & 3, cr = u >> 4;
    int col = cr % 66, row = cr / 66;           // row 0..3
    uint4 raw = *(const uint4*)&y0w[((size_t)((n * H1 + r0 * 2 + row) * H1 + col)) * CC
                                    + cic * 32 + cig * 8];
    *(uint4*)&Alds[cic * A2PL + (row * 66 + col) * A2STR + cig * 8] = raw;
  }
  __syncthreads();

#pragma unroll 1
  for (int ii = 0; ii < 4; ++ii) {
    int i = ip * 4 + ii;
    const unsigned short* Bp = (const unsigned short*)(ws + BP1S_OFF) + (size_t)i * 147456;

    f32x4 acc[4][4];
#pragma unroll
    for (int mf = 0; mf < 4; ++mf)
#pragma unroll
      for (int nf = 0; nf < 4; ++nf) acc[mf][nf] = (f32x4){0.f, 0.f, 0.f, 0.f};

    __builtin_amdgcn_s_setprio(1);
    for (int cic = 0; cic < 4; ++cic) {
      uint4 mv = *(const uint4*)&msk[ii][(cic << 2) | l4][0];
#pragma unroll
      for (int kk = 0; kk < 9; ++kk) {
        int ky = kk / 3, kx = kk % 3;
        bf16x8 af[4], bfr[4];
#pragma unroll
        for (int mf = 0; mf < 4; ++mf) {
          int row = wr + ky;                          // 0..3
          int col = mf * 16 + l15 + kx;               // 0..65
          uint4 raw = *(const uint4*)&Alds[cic * A2PL + (row * 66 + col) * A2STR + l4 * 8];
          union { uint4 u; bf16x8 v; } cv_;
          cv_.u.x = selbf(raw.x, mv.x);
          cv_.u.y = selbf(raw.y, mv.y);
          cv_.u.z = selbf(raw.z, mv.z);
          cv_.u.w = selbf(raw.w, mv.w);
          af[mf] = cv_.v;
        }
#pragma unroll
        for (int nf = 0; nf < 4; ++nf)
          bfr[nf] = *(const bf16x8*)&Bp[(((kk * 4 + cic) * 8 + wc * 4 + nf) * 64 + lane) * 8];
#pragma unroll
        for (int mf = 0; mf < 4; ++mf)
#pragma unroll
          for (int nf = 0; nf < 4; ++nf)
            acc[mf][nf] = __builtin_amdgcn_mfma_f32_16x16x32_bf16(af[mf], bfr[nf], acc[mf][nf], 0, 0, 0);
      }
    }
    __builtin_amdgcn_s_setprio(0);

    // epilogue for sentence i: relu((acc+bc1)*g1)*W2d, reduce over co
    float part[4][4];
#pragma unroll
    for (int mf = 0; mf < 4; ++mf)
#pragma unroll
      for (int rg = 0; rg < 4; ++rg) part[mf][rg] = 0.f;
#pragma unroll
    for (int nf = 0; nf < 4; ++nf) {
      int co = wc * 64 + nf * 16 + l15;
      float bcv = bc1[co];
      float gv = g1[i * CC + co];
      float wv = W2d[co];
#pragma unroll
      for (int mf = 0; mf < 4; ++mf)
#pragma unroll
        for (int rg = 0; rg < 4; ++rg) {
          float z = (acc[mf][nf][rg] + bcv) * gv;
          part[mf][rg] += fmaxf(z, 0.f) * wv;
        }
    }
#pragma unroll
    for (int mask = 1; mask < 16; mask <<= 1)
#pragma unroll
      for (int mf = 0; mf < 4; ++mf)
#pragma unroll
        for (int rg = 0; rg < 4; ++rg)
          part[mf][rg] += __shfl_xor(part[mf][rg], mask, 64);
    if (l15 == 0) {
#pragma unroll
      for (int mf = 0; mf < 4; ++mf)
#pragma unroll
        for (int rg = 0; rg < 4; ++rg)
          redl[wc][wr][mf * 16 + l4 * 4 + rg] = part[mf][rg];
    }
    __syncthreads();
    if (t < 128) {
      int row = t >> 6, col = t & 63;             // row 0..1
      int rowg = r0 * 2 + row;
      float v = redl[0][row][col] + redl[1][row][col];
      float logit = w1m[rowg * TT + col] * v + b2d[0];
      float sig = 1.f / (1.f + expf(-logit));
      bool m = (v_mask[rowg * TT + col] > 0.f) && (col < valid_num[n]);
      int p = rowg * TT + col;
      if (i == n) {
        ws[S_OFF + i * PP + p] = m ? sig : -INFINITY;           // for hard-neg mining
        out[1 + i * PP + p] = m ? sig : NEG_SENTINEL;           // positive_map output
      }
      unsigned long long key = 0ull;
      if (m) key = ((unsigned long long)__float_as_uint(sig) << 32)
                   | (unsigned long long)(0xFFFFFFFFu - (unsigned)p);
#pragma unroll
      for (int mk = 1; mk < 64; mk <<= 1) {
        unsigned lo = __shfl_xor((unsigned)key, mk, 64);
        unsigned hi = __shfl_xor((unsigned)(key >> 32), mk, 64);
        unsigned long long o = ((unsigned long long)hi << 32) | lo;
        if (o > key) key = o;
      }
      if (lane == 0) kred[w] = key;
    }
    __syncthreads();
    if (t == 0) {
      unsigned long long k = kred[0];
      if (kred[1] > k) k = kred[1];
      if (k) atomicMax(&scp[i * 8 + n], k);
    }
  }
}

// hard-negative mining: one block per sentence (8 blocks x 256 thr)
__global__ __launch_bounds__(256) void mine_kernel(
    const float* __restrict__ iou_maps, const float* __restrict__ lam,
    float* __restrict__ ws)
{
  __shared__ float wred[4];
  int i = blockIdx.x;
  int t = threadIdx.x, lane = t & 63, w = t >> 6;
  const unsigned long long* scp = (const unsigned long long*)(ws + SCP_OFF);

  unsigned long long dk = scp[i * 9];                  // diag (i,i)
  float diag_sc = __uint_as_float((unsigned)(dk >> 32));
  int pidx = (int)(0xFFFFFFFFu - (unsigned)(dk & 0xFFFFFFFFu));
  float lamv = lam[0];
  const float* row = iou_maps + (size_t)pidx * PP;
  const float* si = ws + S_OFF + (size_t)i * PP;
  float hv = -INFINITY;
  for (int p = t; p < PP; p += 256) {
    float v = si[p];
    if (row[p] < lamv && isfinite(v)) hv = fmaxf(hv, v);
  }
#pragma unroll
  for (int m = 1; m < 64; m <<= 1) hv = fmaxf(hv, __shfl_xor(hv, m, 64));
  if (lane == 0) wred[w] = hv;
  __syncthreads();
  if (t == 0) {
    float h = fmaxf(fmaxf(wred[0], wred[1]), fmaxf(wred[2], wred[3]));
    ws[NL_OFF + i] = fmaxf(0.f, MARGINF + h - diag_sc);
  }
}

// final loss: 1 wave, sorting-network top-3 (unchanged math)
__global__ __launch_bounds__(64) void loss_kernel(
    float* __restrict__ ws, float* __restrict__ out)
{
  __shared__ float scsh[64];
  int lane = threadIdx.x;
  const unsigned long long* scp = (const unsigned long long*)(ws + SCP_OFF);
  scsh[lane] = __uint_as_float((unsigned)(scp[lane] >> 32));
  __syncthreads();

  float partial = 0.f;
  if (lane < 16) {
    int r = lane & 7;
    bool im = lane >= 8;
    float diag = scsh[r * 8 + r];
    float v[8];
#pragma unroll
    for (int j = 0; j < 8; ++j) {
      float scv = im ? scsh[j * 8 + r] : scsh[r * 8 + j];
      float h = fmaxf(0.f, MARGINF + scv - diag);
      v[j] = (j == r) ? 0.f : h;
    }
#define CE(a, b) { float mx = fmaxf(v[a], v[b]); float mn = fminf(v[a], v[b]); v[a] = mx; v[b] = mn; }
    CE(0,1) CE(2,3) CE(4,5) CE(6,7)
    CE(0,2) CE(1,3) CE(4,6) CE(5,7)
    CE(1,2) CE(5,6)
    CE(0,4) CE(1,5) CE(2,6) CE(3,7)
    CE(2,4) CE(3,5)
    CE(1,2) CE(3,4) CE(5,6)
#undef CE
    partial = v[0] + v[1] + v[2];
  } else if (lane >= 16 && lane < 24) {
    partial = ws[NL_OFF + lane - 16];
  }
#pragma unroll
  for (int m = 1; m < 64; m <<= 1) partial += __shfl_xor(partial, m, 64);
  if (lane == 0) out[0] = partial * 0.125f;
}

extern "C" void kernel_launch(void* const* d_in, const int* in_sizes, int n_in,
                              void* d_out, int out_size, void* d_ws, size_t ws_size,
                              hipStream_t stream)
{
  const float* v_map     = (const float*)d_in[0];
  const float* words     = (const float*)d_in[1];
  const float* w_masks   = (const float*)d_in[2];
  const float* v_mask    = (const float*)d_in[3];
  const int*   valid_num = (const int*)d_in[4];
  const float* iou_maps  = (const float*)d_in[5];
  const float* lam       = (const float*)d_in[6];
  const float* Wc0 = (const float*)d_in[7];
  const float* bc0 = (const float*)d_in[8];
  const float* Wc1 = (const float*)d_in[9];
  const float* bc1 = (const float*)d_in[10];
  const float* Wp0 = (const float*)d_in[11];
  const float* bp0 = (const float*)d_in[12];
  const float* Wp1 = (const float*)d_in[13];
  const float* bp1 = (const float*)d_in[14];
  const float* W2d = (const float*)d_in[15];
  const float* b2d = (const float*)d_in[16];
  float* ws  = (float*)d_ws;
  float* out = (float*)d_out;

  hipLaunchKernelGGL(setup_kernel, dim3(1097), dim3(256), 0, stream,
                     v_map, v_mask, Wc0, words, w_masks, Wp0, bp0, Wp1, bp1, ws);
  hipLaunchKernelGGL(conv1_mfma, dim3(1632), dim3(256), 0, stream, bc0, Wc1, ws);
  hipLaunchKernelGGL(conv2_mfma, dim3(32, 16), dim3(256), 0, stream,
                     bc1, W2d, b2d, v_mask, valid_num, ws, out);
  hipLaunchKernelGGL(mine_kernel, dim3(8), dim3(256), 0, stream, iou_maps, lam, ws);
  hipLaunchKernelGGL(loss_kernel, dim3(1), dim3(64), 0, stream, ws, out);
}

// Round 15
// 132.744 us; speedup vs baseline: 1.2965x; 1.2965x over previous
//
#include <hip/hip_runtime.h>
#include <hip/hip_bf16.h>
#include <math.h>

#define BB 8
#define CC 128
#define DD 64
#define TT 64
#define PP 4096
#define H1 66
#define LW 20
#define MARGINF 0.1f
#define NEG_SENTINEL -1.0e30f

// workspace layout (float offsets)
#define Y0_OFF   0            // y0w bf16 channel-last [8][66][66][128] = 2230272 f
#define VT_OFF   2230272      // vT bf16 [8][64][64][128] = 2097152 f
#define BP0_OFF  4327424      // Bpack(Wc0) 16x16 layout = 73728 f
#define NL_OFF   4401152      // per-sentence neg-loss [8] (old BP1 slot, unused gap)
#define W0_OFF   4479236      // weight0 [66][66] = 4356
#define W1_OFF   4483592      // weight1 [64][64] = 4096
#define G0_OFF   4487688      // [8][128]
#define G1_OFF   4488712      // [8][128]
#define S_OFF    4489736      // si [8][4096] = 32768 (diag maps only)
#define SCP_OFF  4522504      // packed scores u64 [64] = 128 f
#define BP1S_OFF 4522632      // 8x gate-scaled Bpack(Wc1*g0[i]) = 8*73728 f = 589824 f
// total ≈ 5112456 floats ≈ 20.5 MB

typedef __attribute__((ext_vector_type(8))) short bf16x8;
typedef __attribute__((ext_vector_type(4))) float f32x4;

// LDS (row,col) stride in shorts: 44 (=88B), conflict-light b128 access
#define ASTR 44

__device__ __forceinline__ unsigned f2bf(float f) {
  union { float f; unsigned u; } v; v.f = f;
  unsigned r = v.u + 0x7fffu + ((v.u >> 16) & 1u);   // RNE (setup only)
  return r >> 16;
}
__device__ __forceinline__ float bf2f(unsigned hw) {
  union { unsigned u; float f; } v; v.u = hw << 16;
  return v.f;
}
// native cast: compiler emits v_cvt_pk for pairs (m240)
__device__ __forceinline__ unsigned cvt_bf(float x) {
  __hip_bfloat16 h = __float2bfloat16(x);
  union { __hip_bfloat16 h; unsigned short u; } cv; cv.h = h;
  return (unsigned)cv.u;
}

// sign-select on 2 packed bf16: keep half iff sign(v) == wanted sign bit in W.
// relu(g*v)*Wc1 == select(v) * (Wc1*g), select(v) = g>0 ? max(v,0) : min(v,0)
__device__ __forceinline__ unsigned selbf(unsigned d, unsigned W) {
  unsigned diff = (d ^ W) & 0x80008000u;     // sign mismatch bits
  unsigned full = (diff >> 15) * 0xFFFFu;    // expand to half-word masks
  return d & ~full;                          // zero mismatched halves
}

// ---------------- setup + gates fused (B1S lives in conv1 launch, so setup
// no longer reads g0 and gates can ride along as blocks 1089..1096)
__global__ __launch_bounds__(256) void setup_kernel(
    const float* __restrict__ vmap, const float* __restrict__ v_mask,
    const float* __restrict__ Wc0,
    const float* __restrict__ words, const float* __restrict__ w_masks,
    const float* __restrict__ Wp0, const float* __restrict__ bp0,
    const float* __restrict__ Wp1, const float* __restrict__ bp1,
    float* __restrict__ ws)
{
  __shared__ float smem[64 * 129];
  int bid = blockIdx.x;
  int t = threadIdx.x;

  if (bid < 576) {
    // B0 pack (unscaled)
    unsigned short* dst = (unsigned short*)(ws + BP0_OFF);
    int idx = bid * 256 + t;
    int j    = idx & 7;
    int lane = (idx >> 3) & 63;
    int cog  = (idx >> 9) & 7;
    int cic  = (idx >> 12) & 3;
    int kk   = idx >> 14;
    int co = cog * 16 + (lane & 15);
    int ci = cic * 32 + (lane >> 4) * 8 + j;
    dst[idx] = (unsigned short)f2bf(Wc0[(co * CC + ci) * 9 + kk]);
  } else if (bid < 1088) {
    unsigned short* vT = (unsigned short*)(ws + VT_OFF);
    int b = bid - 576;                   // 576 % 8 == 0 -> XCD = b & 7
    int n = b & 7, y = b >> 3;           // XCD-aligned: vT[n] stays in XCD n's L2
    int x = t & 63, c4 = t >> 6;
    for (int rep = 0; rep < 32; ++rep) {
      int ci = rep * 4 + c4;
      smem[x * 129 + ci] = vmap[(((size_t)n * CC + ci) * DD + y) * TT + x];
    }
    __syncthreads();
    for (int rep = 0; rep < 16; ++rep) {
      int v = t + rep * 256;
      int xx = v >> 6, cip = v & 63;
      float a = smem[xx * 129 + cip * 2];
      float b2 = smem[xx * 129 + cip * 2 + 1];
      unsigned pk = f2bf(a) | (f2bf(b2) << 16);
      *(unsigned*)&vT[(((size_t)(n * DD + y) * TT + xx)) * CC + cip * 2] = pk;
    }
  } else if (bid == 1088) {
    if (t < 128) ((unsigned*)(ws + SCP_OFF))[t] = 0u;   // zero packed scores
    float* w0 = ws + W0_OFF;
    float* w1 = ws + W1_OFF;
    for (int idx = t; idx < H1 * H1; idx += 256) {
      int y = idx / H1, x = idx % H1;
      float cnt = 0.f;
      for (int ky = 0; ky < 3; ++ky)
        for (int kx = 0; kx < 3; ++kx) {
          int iy = y + ky - 2, ix = x + kx - 2;
          if (iy >= 0 && iy < DD && ix >= 0 && ix < TT) cnt += v_mask[iy * TT + ix];
        }
      w0[idx] = (cnt > 0.f) ? 1.f / fmaxf(cnt, 1.f) : 0.f;
    }
    __syncthreads();
    for (int idx = t; idx < DD * TT; idx += 256) {
      int y = idx / TT, x = idx % TT;
      float cnt = 0.f;
      for (int ky = 0; ky < 3; ++ky)
        for (int kx = 0; kx < 3; ++kx)
          cnt += (w0[(y + ky) * H1 + (x + kx)] > 0.f) ? 1.f : 0.f;
      w1[idx] = (cnt > 0.f) ? 1.f / fmaxf(cnt, 1.f) : 0.f;
    }
  } else {
    // gates: pooled words -> g0,g1 (consumed by NEXT launch's B1S blocks)
    int i = bid - 1089;
    if (t < CC) {
      float wsum = 0.f, acc = 0.f;
      for (int l = 0; l < LW; ++l) {
        float wm = w_masks[i * LW + l];
        wsum += wm;
        acc += words[(i * LW + l) * CC + t] * wm;
      }
      smem[t] = acc / fmaxf(wsum, 1.f);
    }
    __syncthreads();
    {
      int c = t & 127;
      const float* Wp = (t < 128) ? Wp0 : Wp1;
      const float* bp = (t < 128) ? bp0 : bp1;
      float a = bp[c];
      for (int k = 0; k < CC; ++k) a += smem[k] * Wp[k * CC + c];
      float g = tanhf(a);
      float* gout = ws + ((t < 128) ? G0_OFF : G1_OFF);
      gout[i * CC + c] = g;
    }
  }
}

// conv1 (co-split: 1 row x 64 co per block, grid 1056 -> ~4 blocks/CU feed)
// + B1S pack riding as blocks 1056..1631 (fills idle CUs; only needs g0
// from the previous launch). XCD-aligned n = id&7 (R25, kept).
__global__ __launch_bounds__(256, 3) void conv1_mfma(
    const float* __restrict__ bc0, const float* __restrict__ Wc1,
    float* __restrict__ ws)
{
  __shared__ unsigned short Alds[3 * 68 * ASTR];   // 17952 B

  int t = threadIdx.x;
  int id = blockIdx.x;

  if (id >= 1056) {
    // B1S pack: read each Wc1 element ONCE, write 8 gate-scaled copies
    float* smem = (float*)Alds;                    // 4KB alias
    for (int v = t; v < 8 * CC; v += 256) smem[v] = ws[G0_OFF + v];
    __syncthreads();
    int idx = (id - 1056) * 256 + t;
    int j    = idx & 7;
    int lane = (idx >> 3) & 63;
    int cog  = (idx >> 9) & 7;
    int cic  = (idx >> 12) & 3;
    int kk   = idx >> 14;
    int co = cog * 16 + (lane & 15);
    int ci = cic * 32 + (lane >> 4) * 8 + j;
    float wv = Wc1[(co * CC + ci) * 9 + kk];
    unsigned short* dst = (unsigned short*)(ws + BP1S_OFF);
#pragma unroll
    for (int si = 0; si < 8; ++si)
      dst[si * 147456 + idx] = (unsigned short)f2bf(wv * smem[si * CC + ci]);
    return;
  }

  const unsigned short* vT = (const unsigned short*)(ws + VT_OFF);
  const unsigned short* Bp = (const unsigned short*)(ws + BP0_OFF);
  const float* w0arr = ws + W0_OFF;
  unsigned short* y0w = (unsigned short*)(ws + Y0_OFF);

  int n  = id & 7;                         // XCD-aligned
  int ch = (id >> 3) & 1;                  // co half 0..1
  int r0 = id >> 4;                        // output row 0..65
  int lane = t & 63, w = t >> 6;           // w = 16-co group within half
  int l15 = lane & 15, l4 = lane >> 4;
  int s = ch * 4 + w;                      // 16-co group 0..7
  int co0 = s * 16;

  f32x4 acc[5];
#pragma unroll
  for (int mf = 0; mf < 5; ++mf) acc[mf] = (f32x4){0.f, 0.f, 0.f, 0.f};

  for (int cic = 0; cic < 4; ++cic) {
    __syncthreads();
    for (int u = t; u < 816; u += 256) {
      int cig = u & 3, rest = u >> 2;
      int col = rest % 68, r = rest / 68;
      int iy = r0 - 2 + r, ix = col - 2;
      uint4 val = {0u, 0u, 0u, 0u};
      if (iy >= 0 && iy < DD && ix >= 0 && ix < TT)
        val = *(const uint4*)&vT[(((size_t)(n * DD + iy) * TT + ix)) * CC + cic * 32 + cig * 8];
      *(uint4*)&Alds[(r * 68 + col) * ASTR + cig * 8] = val;
    }
    __syncthreads();
    __builtin_amdgcn_s_setprio(1);
#pragma unroll
    for (int kk = 0; kk < 9; ++kk) {
      int ky = kk / 3, kx = kk % 3;
      bf16x8 af[5], bfr;
#pragma unroll
      for (int mf = 0; mf < 5; ++mf) {
        int c = mf * 16 + l15;
        int cc = c > 65 ? 65 : c;
        af[mf] = *(const bf16x8*)&Alds[(ky * 68 + cc + kx) * ASTR + l4 * 8];
      }
      bfr = *(const bf16x8*)&Bp[(((kk * 4 + cic) * 8 + s) * 64 + lane) * 8];
#pragma unroll
      for (int mf = 0; mf < 5; ++mf)
        acc[mf] = __builtin_amdgcn_mfma_f32_16x16x32_bf16(af[mf], bfr, acc[mf], 0, 0, 0);
    }
    __builtin_amdgcn_s_setprio(0);
  }

  int y = r0;
  {
    int co = co0 + l15;
    float bcv = bc0[co];
#pragma unroll
    for (int mf = 0; mf < 5; ++mf)
#pragma unroll
      for (int rg = 0; rg < 4; ++rg) {
        int c = mf * 16 + l4 * 4 + rg;
        if (c < H1) {
          float v = (acc[mf][rg] + bcv) * w0arr[y * H1 + c];
          y0w[((size_t)(n * H1 + y) * H1 + c) * CC + co] = (unsigned short)cvt_bf(v);
        }
      }
  }
}

// conv2: byte-identical to R26 (measured best, 81.4us): 2-row tiles,
// launch_bounds(256,3), selbf staging, global-B MFMA cluster.
__global__ __launch_bounds__(256, 3) void conv2_mfma(
    const float* __restrict__ bc1, const float* __restrict__ W2d,
    const float* __restrict__ b2d, const float* __restrict__ v_mask,
    const int* __restrict__ valid_num, float* __restrict__ ws,
    float* __restrict__ out)
{
  const unsigned short* y0w = (const unsigned short*)(ws + Y0_OFF);
  const float* w1m = ws + W1_OFF;
  const float* g0 = ws + G0_OFF;
  const float* g1 = ws + G1_OFF;
  unsigned long long* scp = (unsigned long long*)(ws + SCP_OFF);

  __shared__ unsigned short Alds[4 * 66 * ASTR];   // 23232 B
  __shared__ unsigned msk[16][4];                  // sign masks per (cic,cig)
  __shared__ float redl[2][2][64];
  __shared__ unsigned long long kred[2];

  int t = threadIdx.x;
  int r0 = blockIdx.x;                        // output rows r0*2, r0*2+1 (r0 in 0..31)
  int i = blockIdx.y & 7, n = blockIdx.y >> 3;   // n-major: L2 locality on y0w[n]
  int lane = t & 63, w = t >> 6;
  int wr = w >> 1, wc = w & 1;                // wr = row, wc = co half
  int l15 = lane & 15, l4 = lane >> 4;

  const unsigned short* Bp = (const unsigned short*)(ws + BP1S_OFF) + (size_t)i * 147456;

  if (t < 16) {                               // t = cic*4+cig -> channels t*8..t*8+7
    int ch = t * 8;
    msk[t][0] = (g0[i * CC + ch + 0] > 0.f ? 0u : 0x8000u) | (g0[i * CC + ch + 1] > 0.f ? 0u : 0x80000000u);
    msk[t][1] = (g0[i * CC + ch + 2] > 0.f ? 0u : 0x8000u) | (g0[i * CC + ch + 3] > 0.f ? 0u : 0x80000000u);
    msk[t][2] = (g0[i * CC + ch + 4] > 0.f ? 0u : 0x8000u) | (g0[i * CC + ch + 5] > 0.f ? 0u : 0x80000000u);
    msk[t][3] = (g0[i * CC + ch + 6] > 0.f ? 0u : 0x8000u) | (g0[i * CC + ch + 7] > 0.f ? 0u : 0x80000000u);
  }

  f32x4 acc[4][4];
#pragma unroll
  for (int mf = 0; mf < 4; ++mf)
#pragma unroll
    for (int nf = 0; nf < 4; ++nf) acc[mf][nf] = (f32x4){0.f, 0.f, 0.f, 0.f};

  for (int cic = 0; cic < 4; ++cic) {
    __syncthreads();
    // stage 4 rows x 66 cols x 32ci: 1056 uint4s; select applied via sign bits
    {
      uint4 mv = *(const uint4*)&msk[(cic << 2) | (t & 3)][0];
      for (int u = t; u < 1056; u += 256) {
        int cig = u & 3, cr = u >> 2;
        int col = cr % 66, row = cr / 66;       // row 0..3
        const unsigned short* src = y0w
            + ((size_t)((n * H1 + r0 * 2 + row) * H1 + col)) * CC + cic * 32 + cig * 8;
        uint4 raw = *(const uint4*)src;
        uint4 pk;
        pk.x = selbf(raw.x, mv.x);
        pk.y = selbf(raw.y, mv.y);
        pk.z = selbf(raw.z, mv.z);
        pk.w = selbf(raw.w, mv.w);
        *(uint4*)&Alds[(row * 66 + col) * ASTR + cig * 8] = pk;
      }
    }
    __syncthreads();
    __builtin_amdgcn_s_setprio(1);
#pragma unroll
    for (int kk = 0; kk < 9; ++kk) {
      int ky = kk / 3, kx = kk % 3;
      bf16x8 af[4], bfr[4];
#pragma unroll
      for (int mf = 0; mf < 4; ++mf) {
        int row = wr + ky;                          // 0..3
        int col = mf * 16 + l15 + kx;               // 0..65
        af[mf] = *(const bf16x8*)&Alds[(row * 66 + col) * ASTR + l4 * 8];
      }
#pragma unroll
      for (int nf = 0; nf < 4; ++nf)
        bfr[nf] = *(const bf16x8*)&Bp[(((kk * 4 + cic) * 8 + wc * 4 + nf) * 64 + lane) * 8];
#pragma unroll
      for (int mf = 0; mf < 4; ++mf)
#pragma unroll
        for (int nf = 0; nf < 4; ++nf)
          acc[mf][nf] = __builtin_amdgcn_mfma_f32_16x16x32_bf16(af[mf], bfr[nf], acc[mf][nf], 0, 0, 0);
    }
    __builtin_amdgcn_s_setprio(0);
  }

  // epilogue: relu((acc+bc1)*g1)*W2d, reduce over co; weight1 factored out (w1>=0)
  float part[4][4];
#pragma unroll
  for (int mf = 0; mf < 4; ++mf)
#pragma unroll
    for (int rg = 0; rg < 4; ++rg) part[mf][rg] = 0.f;
#pragma unroll
  for (int nf = 0; nf < 4; ++nf) {
    int co = wc * 64 + nf * 16 + l15;
    float bcv = bc1[co];
    float gv = g1[i * CC + co];
    float wv = W2d[co];
#pragma unroll
    for (int mf = 0; mf < 4; ++mf)
#pragma unroll
      for (int rg = 0; rg < 4; ++rg) {
        float z = (acc[mf][nf][rg] + bcv) * gv;
        part[mf][rg] += fmaxf(z, 0.f) * wv;
      }
  }
#pragma unroll
  for (int mask = 1; mask < 16; mask <<= 1)
#pragma unroll
    for (int mf = 0; mf < 4; ++mf)
#pragma unroll
      for (int rg = 0; rg < 4; ++rg)
        part[mf][rg] += __shfl_xor(part[mf][rg], mask, 64);
  if (l15 == 0) {
#pragma unroll
    for (int mf = 0; mf < 4; ++mf)
#pragma unroll
      for (int rg = 0; rg < 4; ++rg)
        redl[wc][wr][mf * 16 + l4 * 4 + rg] = part[mf][rg];
  }
  __syncthreads();
  if (t < 128) {
    int row = t >> 6, col = t & 63;             // row 0..1
    int rowg = r0 * 2 + row;
    float v = redl[0][row][col] + redl[1][row][col];
    float logit = w1m[rowg * TT + col] * v + b2d[0];
    float sig = 1.f / (1.f + expf(-logit));
    bool m = (v_mask[rowg * TT + col] > 0.f) && (col < valid_num[n]);
    int p = rowg * TT + col;
    if (i == n) {
      ws[S_OFF + i * PP + p] = m ? sig : -INFINITY;           // for hard-neg mining
      out[1 + i * PP + p] = m ? sig : NEG_SENTINEL;           // positive_map output
    }
    unsigned long long key = 0ull;
    if (m) key = ((unsigned long long)__float_as_uint(sig) << 32)
                 | (unsigned long long)(0xFFFFFFFFu - (unsigned)p);
#pragma unroll
    for (int mk = 1; mk < 64; mk <<= 1) {
      unsigned lo = __shfl_xor((unsigned)key, mk, 64);
      unsigned hi = __shfl_xor((unsigned)(key >> 32), mk, 64);
      unsigned long long o = ((unsigned long long)hi << 32) | lo;
      if (o > key) key = o;
    }
    if (lane == 0) kred[w] = key;
  }
  __syncthreads();
  if (t == 0) {
    unsigned long long k = kred[0];
    if (kred[1] > k) k = kred[1];
    if (k) atomicMax(&scp[i * 8 + n], k);
  }
}

// hard-negative mining: one block per sentence (8 blocks x 256 thr)
__global__ __launch_bounds__(256) void mine_kernel(
    const float* __restrict__ iou_maps, const float* __restrict__ lam,
    float* __restrict__ ws)
{
  __shared__ float wred[4];
  int i = blockIdx.x;
  int t = threadIdx.x, lane = t & 63, w = t >> 6;
  const unsigned long long* scp = (const unsigned long long*)(ws + SCP_OFF);

  unsigned long long dk = scp[i * 9];                  // diag (i,i)
  float diag_sc = __uint_as_float((unsigned)(dk >> 32));
  int pidx = (int)(0xFFFFFFFFu - (unsigned)(dk & 0xFFFFFFFFu));
  float lamv = lam[0];
  const float* row = iou_maps + (size_t)pidx * PP;
  const float* si = ws + S_OFF + (size_t)i * PP;
  float hv = -INFINITY;
  for (int p = t; p < PP; p += 256) {
    float v = si[p];
    if (row[p] < lamv && isfinite(v)) hv = fmaxf(hv, v);
  }
#pragma unroll
  for (int m = 1; m < 64; m <<= 1) hv = fmaxf(hv, __shfl_xor(hv, m, 64));
  if (lane == 0) wred[w] = hv;
  __syncthreads();
  if (t == 0) {
    float h = fmaxf(fmaxf(wred[0], wred[1]), fmaxf(wred[2], wred[3]));
    ws[NL_OFF + i] = fmaxf(0.f, MARGINF + h - diag_sc);
  }
}

// final loss: 1 wave, sorting-network top-3 (unchanged math)
__global__ __launch_bounds__(64) void loss_kernel(
    float* __restrict__ ws, float* __restrict__ out)
{
  __shared__ float scsh[64];
  int lane = threadIdx.x;
  const unsigned long long* scp = (const unsigned long long*)(ws + SCP_OFF);
  scsh[lane] = __uint_as_float((unsigned)(scp[lane] >> 32));
  __syncthreads();

  float partial = 0.f;
  if (lane < 16) {
    int r = lane & 7;
    bool im = lane >= 8;
    float diag = scsh[r * 8 + r];
    float v[8];
#pragma unroll
    for (int j = 0; j < 8; ++j) {
      float scv = im ? scsh[j * 8 + r] : scsh[r * 8 + j];
      float h = fmaxf(0.f, MARGINF + scv - diag);
      v[j] = (j == r) ? 0.f : h;
    }
#define CE(a, b) { float mx = fmaxf(v[a], v[b]); float mn = fminf(v[a], v[b]); v[a] = mx; v[b] = mn; }
    CE(0,1) CE(2,3) CE(4,5) CE(6,7)
    CE(0,2) CE(1,3) CE(4,6) CE(5,7)
    CE(1,2) CE(5,6)
    CE(0,4) CE(1,5) CE(2,6) CE(3,7)
    CE(2,4) CE(3,5)
    CE(1,2) CE(3,4) CE(5,6)
#undef CE
    partial = v[0] + v[1] + v[2];
  } else if (lane >= 16 && lane < 24) {
    partial = ws[NL_OFF + lane - 16];
  }
#pragma unroll
  for (int m = 1; m < 64; m <<= 1) partial += __shfl_xor(partial, m, 64);
  if (lane == 0) out[0] = partial * 0.125f;
}

extern "C" void kernel_launch(void* const* d_in, const int* in_sizes, int n_in,
                              void* d_out, int out_size, void* d_ws, size_t ws_size,
                              hipStream_t stream)
{
  const float* v_map     = (const float*)d_in[0];
  const float* words     = (const float*)d_in[1];
  const float* w_masks   = (const float*)d_in[2];
  const float* v_mask    = (const float*)d_in[3];
  const int*   valid_num = (const int*)d_in[4];
  const float* iou_maps  = (const float*)d_in[5];
  const float* lam       = (const float*)d_in[6];
  const float* Wc0 = (const float*)d_in[7];
  const float* bc0 = (const float*)d_in[8];
  const float* Wc1 = (const float*)d_in[9];
  const float* bc1 = (const float*)d_in[10];
  const float* Wp0 = (const float*)d_in[11];
  const float* bp0 = (const float*)d_in[12];
  const float* Wp1 = (const float*)d_in[13];
  const float* bp1 = (const float*)d_in[14];
  const float* W2d = (const float*)d_in[15];
  const float* b2d = (const float*)d_in[16];
  float* ws  = (float*)d_ws;
  float* out = (float*)d_out;

  hipLaunchKernelGGL(setup_kernel, dim3(1097), dim3(256), 0, stream,
                     v_map, v_mask, Wc0, words, w_masks, Wp0, bp0, Wp1, bp1, ws);
  hipLaunchKernelGGL(conv1_mfma, dim3(1632), dim3(256), 0, stream, bc0, Wc1, ws);
  hipLaunchKernelGGL(conv2_mfma, dim3(32, 64), dim3(256), 0, stream,
                     bc1, W2d, b2d, v_mask, valid_num, ws, out);
  hipLaunchKernelGGL(mine_kernel, dim3(8), dim3(256), 0, stream, iou_maps, lam, ws);
  hipLaunchKernelGGL(loss_kernel, dim3(1), dim3(64), 0, stream, ws, out);
}